// Round 3
// baseline (107.408 us; speedup 1.0000x reference)
//
#include <hip/hip_runtime.h>

#define BB 8
#define HH 64
#define WW 2048
#define NC 20

// tile: 4 rows x 64 cols per 256-thread block
// depth halo = 4 (9x9 reach, 0.0-padded = exact reference unfold zero-pad)
// label halo = 2 (5x5 reach, 0-padded)
// Register discipline: rotating 5x9 depth row-window (45 regs, static mod-5
// slot indices under full unroll) instead of the whole 9x9 (81 regs).

__global__ __launch_bounds__(256, 4) void knn_refine(
    const float* __restrict__ depth,
    const int*   __restrict__ label,
    const float* __restrict__ wker,
    int*         __restrict__ out)
{
    __shared__ float sD[12][72];
    __shared__ int   sL[8][68];

    const int b  = blockIdx.z;
    const int y0 = blockIdx.y * 4;
    const int x0 = blockIdx.x * 64;
    const int t  = threadIdx.x;

    const float* Db = depth + (size_t)b * (HH * WW);
    const int*   Lb = label + (size_t)b * (HH * WW);

    // ---- stage depth tile (+4 halo), OOB pad = 0.0 ----
    for (int idx = t; idx < 12 * 72; idx += 256) {
        int ry = idx / 72, rx = idx - ry * 72;
        int gyy = y0 + ry - 4, gxx = x0 + rx - 4;
        float v = 0.0f;
        if (gyy >= 0 && gyy < HH && gxx >= 0 && gxx < WW) v = Db[gyy * WW + gxx];
        sD[ry][rx] = v;
    }
    // ---- stage label tile (+2 halo), OOB pad = 0 ----
    for (int idx = t; idx < 8 * 68; idx += 256) {
        int ry = idx / 68, rx = idx - ry * 68;
        int gyy = y0 + ry - 2, gxx = x0 + rx - 2;
        int v = 0;
        if (gyy >= 0 && gyy < HH && gxx >= 0 && gxx < WW) v = Lb[gyy * WW + gxx];
        sL[ry][rx] = v;
    }
    __syncthreads();

    const int px = t & 63;
    const int py = t >> 6;
    const int gy = y0 + py;
    const int gx = x0 + px;

    // anchor-in-image masks as exact 0/1 floats (conv zero-pad in p-space)
    float my[5], mx[5];
#pragma unroll
    for (int d = 0; d < 5; ++d) {
        my[d] = ((unsigned)(gy + d - 2) < (unsigned)HH) ? 1.0f : 0.0f;
        mx[d] = ((unsigned)(gx + d - 2) < (unsigned)WW) ? 1.0f : 0.0f;
    }

    // kernel weights (uniform address -> scalar loads)
    float wv[25];
#pragma unroll
    for (int j = 0; j < 25; ++j) wv[j] = wker[j];

    float dist[25];
#pragma unroll
    for (int k = 0; k < 25; ++k) dist[k] = 0.0f;
    // dist[12] (k-offset (0,0)) stays exactly +0.0: every term is w*|D-D| = 0.

    // ---- rotating 5x9 window: slot s holds global nb-row r with r%5==s ----
    float win[5][9];
#pragma unroll
    for (int r = 0; r < 5; ++r)
#pragma unroll
        for (int c = 0; c < 9; ++c)
            win[r][c] = sD[py + r][px + c];

#pragma unroll
    for (int jy = 0; jy < 5; ++jy) {
        const int cs = (jy + 2) % 5;          // slot of center row (jy+2)
        float wrow[5];
#pragma unroll
        for (int jx = 0; jx < 5; ++jx)
            wrow[jx] = my[jy] * mx[jx] * wv[jy * 5 + jx];  // exact: *1.0 or *0.0

#pragma unroll
        for (int jx = 0; jx < 5; ++jx) {
            const float Dq = win[cs][jx + 2];
            const float wj = wrow[jx];
#pragma unroll
            for (int k = 0; k < 25; ++k) {
                if (k == 12) continue;
                const int ky = k / 5, kx = k % 5;
                const int rs = (jy + ky) % 5;  // compile-time slot
                dist[k] = fmaf(wj, fabsf(win[rs][jx + kx] - Dq), dist[k]);
            }
        }
        // slide window down: load global row jy+5 into slot (jy+5)%5 == jy%5
        if (jy < 4) {
            const int ns = jy % 5;
#pragma unroll
            for (int c = 0; c < 9; ++c)
                win[ns][c] = sD[py + jy + 5][px + c];
        }
    }

    // ---- stable top-5 smallest (strict <, ties -> lower k, = lax.top_k) ----
    int labs[5];
#pragma unroll
    for (int r = 0; r < 5; ++r) {
        float best = 3.4e38f;
        int bi = 0;
#pragma unroll
        for (int k = 0; k < 25; ++k) {
            if (dist[k] < best) { best = dist[k]; bi = k; }
        }
        int ky = (bi * 205) >> 10;            // bi / 5 for bi in [0,25)
        int kx = bi - ky * 5;
        labs[r] = (best > 1.0f) ? NC : sL[py + ky][px + kx];
        if (r < 4) {
#pragma unroll
            for (int k = 0; k < 25; ++k)
                if (k == bi) dist[k] = 3.4e38f;
        }
    }

    // ---- majority vote over 5 labels; argmax ties -> lowest class index ----
    int bestLab = 0, bestCnt = 0;
#pragma unroll
    for (int i = 0; i < 5; ++i) {
        const int li = labs[i];
        int c = 0;
#pragma unroll
        for (int j = 0; j < 5; ++j) c += (labs[j] == li) ? 1 : 0;
        if (li < NC && (c > bestCnt || (c == bestCnt && li < bestLab))) {
            bestCnt = c;
            bestLab = li;
        }
    }

    out[(size_t)b * (HH * WW) + (size_t)gy * WW + gx] = bestLab;
}

extern "C" void kernel_launch(void* const* d_in, const int* in_sizes, int n_in,
                              void* d_out, int out_size, void* d_ws, size_t ws_size,
                              hipStream_t stream) {
    const float* depth = (const float*)d_in[0];
    const int*   label = (const int*)d_in[1];
    const float* wker  = (const float*)d_in[2];
    int*         out   = (int*)d_out;

    dim3 grid(WW / 64, HH / 4, BB);
    knn_refine<<<grid, dim3(256), 0, stream>>>(depth, label, wker, out);
}

// Round 4
// 68.480 us; speedup vs baseline: 1.5685x; 1.5685x over previous
//
#include <hip/hip_runtime.h>

#define BB 8
#define HH 64
#define WW 2048
#define NC 20

// tile: 4 rows x 64 cols per 256-thread block
// depth halo = 4 (9x9 reach, 0.0-padded = exact reference unfold zero-pad:
//   |0 - Dq| = Dq, identical to the reference's padded-neighbor jump)
// label halo = 2 (5x5 reach, 0-padded)
//
// R4 design notes (evidence-driven):
//  - R1 (VGPR=48, compiler folds nb[] into in-loop ds_read): VALUBusy 111%, 65us
//  - R2 (reg-resident nb[81], VGPR=100): occupancy 20%, 69us
//  - R3 (rotating window): scratch spills, 400MB HBM traffic, 107us
//  => keep R1 structure, halve inner-loop VALU ops, keep weights in SGPRs on
//     the (block-uniform) interior fast path.

// dist accumulation for one pixel; W[j] must be indexable with compile-time j.
#define DIST_LOOP(WEXPR)                                                      \
    _Pragma("unroll")                                                         \
    for (int j = 0; j < 25; ++j) {                                            \
        const int jy = j / 5, jx = j % 5;                                     \
        const float Dq = nb[(2 + jy) * 9 + (2 + jx)];                         \
        const float wj = (WEXPR);                                             \
        _Pragma("unroll")                                                     \
        for (int k = 0; k < 25; ++k) {                                        \
            if (k == 12) continue;                                            \
            const int ky = k / 5, kx = k % 5;                                 \
            dist[k] = fmaf(wj, fabsf(nb[(jy + ky) * 9 + (jx + kx)] - Dq),     \
                           dist[k]);                                          \
        }                                                                     \
    }

__global__ __launch_bounds__(256) void knn_refine(
    const float* __restrict__ depth,
    const int*   __restrict__ label,
    const float* __restrict__ wker,
    int*         __restrict__ out)
{
    __shared__ float sD[12][72];
    __shared__ int   sL[8][68];

    const int b  = blockIdx.z;
    const int y0 = blockIdx.y * 4;
    const int x0 = blockIdx.x * 64;
    const int t  = threadIdx.x;

    const float* Db = depth + (size_t)b * (HH * WW);
    const int*   Lb = label + (size_t)b * (HH * WW);

    // ---- stage depth tile (+4 halo), OOB pad = 0.0 ----
    for (int idx = t; idx < 12 * 72; idx += 256) {
        int ry = idx / 72, rx = idx - ry * 72;
        int gyy = y0 + ry - 4, gxx = x0 + rx - 4;
        float v = 0.0f;
        if (gyy >= 0 && gyy < HH && gxx >= 0 && gxx < WW) v = Db[gyy * WW + gxx];
        sD[ry][rx] = v;
    }
    // ---- stage label tile (+2 halo), OOB pad = 0 ----
    for (int idx = t; idx < 8 * 68; idx += 256) {
        int ry = idx / 68, rx = idx - ry * 68;
        int gyy = y0 + ry - 2, gxx = x0 + rx - 2;
        int v = 0;
        if (gyy >= 0 && gyy < HH && gxx >= 0 && gxx < WW) v = Lb[gyy * WW + gxx];
        sL[ry][rx] = v;
    }
    __syncthreads();

    const int px = t & 63;
    const int py = t >> 6;
    const int gy = y0 + py;
    const int gx = x0 + px;

    // kernel weights: uniform address -> scalar loads (SGPR-resident)
    float wv[25];
#pragma unroll
    for (int j = 0; j < 25; ++j) wv[j] = wker[j];

    // 9x9 depth neighborhood; compiler folds these into in-loop ds_reads
    // at its preferred register budget (R1 evidence: VGPR=48).
    float nb[81];
#pragma unroll
    for (int dy = 0; dy < 9; ++dy)
#pragma unroll
        for (int dx = 0; dx < 9; ++dx)
            nb[dy * 9 + dx] = sD[py + dy][px + dx];

    float dist[25];
#pragma unroll
    for (int k = 0; k < 25; ++k) dist[k] = 0.0f;
    // dist[12] (k-offset (0,0)) stays exactly +0.0: every term is w*|D-D| = 0.

    // block-uniform edge test: any pixel in this block with an anchor (p+j,
    // |j|<=2) outside the image needs conv zero-pad masking.
    const bool edgeBlock = (y0 == 0) | (y0 == HH - 4) | (x0 == 0) | (x0 == WW - 64);

    if (!edgeBlock) {
        // hot path (~82% of blocks): weights straight from SGPRs
        DIST_LOOP(wv[j])
    } else {
        // masked path: anchor-OOB taps contribute 0 (conv zero-pad in p-space)
        float my[5], mx[5];
#pragma unroll
        for (int d = 0; d < 5; ++d) {
            my[d] = ((unsigned)(gy + d - 2) < (unsigned)HH) ? 1.0f : 0.0f;
            mx[d] = ((unsigned)(gx + d - 2) < (unsigned)WW) ? 1.0f : 0.0f;
        }
        float wje[25];
#pragma unroll
        for (int j = 0; j < 25; ++j)
            wje[j] = my[j / 5] * mx[j % 5] * wv[j];   // exact: *1.0 or *0.0
        DIST_LOOP(wje[j])
    }

    // ---- stable top-5 smallest (strict <, ties -> lower k, = lax.top_k) ----
    int labs[5];
#pragma unroll
    for (int r = 0; r < 5; ++r) {
        float best = 3.4e38f;
        int bi = 0;
#pragma unroll
        for (int k = 0; k < 25; ++k) {
            if (dist[k] < best) { best = dist[k]; bi = k; }
        }
        int ky = (bi * 205) >> 10;            // bi / 5 for bi in [0,25)
        int kx = bi - ky * 5;
        labs[r] = (best > 1.0f) ? NC : sL[py + ky][px + kx];
        if (r < 4) {
#pragma unroll
            for (int k = 0; k < 25; ++k)
                if (k == bi) dist[k] = 3.4e38f;
        }
    }

    // ---- majority vote over 5 labels; argmax ties -> lowest class index ----
    int bestLab = 0, bestCnt = 0;
#pragma unroll
    for (int i = 0; i < 5; ++i) {
        const int li = labs[i];
        int c = 0;
#pragma unroll
        for (int j = 0; j < 5; ++j) c += (labs[j] == li) ? 1 : 0;
        if (li < NC && (c > bestCnt || (c == bestCnt && li < bestLab))) {
            bestCnt = c;
            bestLab = li;
        }
    }

    out[(size_t)b * (HH * WW) + (size_t)gy * WW + gx] = bestLab;
}

extern "C" void kernel_launch(void* const* d_in, const int* in_sizes, int n_in,
                              void* d_out, int out_size, void* d_ws, size_t ws_size,
                              hipStream_t stream) {
    const float* depth = (const float*)d_in[0];
    const int*   label = (const int*)d_in[1];
    const float* wker  = (const float*)d_in[2];
    int*         out   = (int*)d_out;

    dim3 grid(WW / 64, HH / 4, BB);
    knn_refine<<<grid, dim3(256), 0, stream>>>(depth, label, wker, out);
}